// Round 5
// baseline (352.172 us; speedup 1.0000x reference)
//
#include <hip/hip_runtime.h>
#include <math.h>

#define D 256
#define MARGIN 0.075f
#define PINF_BITS 0x7F800000u

typedef __bf16 bf8_t __attribute__((ext_vector_type(8)));
typedef float f4_t __attribute__((ext_vector_type(4)));

static __device__ __forceinline__ unsigned short f2bf(float x) {
    unsigned u = __float_as_uint(x);
    unsigned r = (u + 0x7fffu + ((u >> 16) & 1u)) >> 16;  // RNE
    return (unsigned short)r;
}

// ---------------------------------------------------------------------------
// zero everything we depend on (ws is re-poisoned to 0xAA before every call)
__global__ void k_init(unsigned* __restrict__ hp, unsigned* __restrict__ nm,
                       unsigned* __restrict__ shn, int np,
                       unsigned* __restrict__ h1, unsigned* __restrict__ h2,
                       unsigned* __restrict__ h1c, unsigned* __restrict__ h2c,
                       unsigned* __restrict__ labhist, float* __restrict__ fsums,
                       unsigned* __restrict__ ctrl) {
    int i = blockIdx.x * 256 + threadIdx.x;
    if (i < np) { hp[i] = 0u; nm[i] = PINF_BITS; shn[i] = PINF_BITS; }
    if (i < 65536) { h1[i] = 0u; h2[i] = 0u; }
    if (i < 1024) { h1c[i] = 0u; h2c[i] = 0u; }
    if (i < 512) labhist[i] = 0u;
    if (i < 8) fsums[i] = 0.f;
    if (i == 0) ctrl[5] = 0u;
}

// ---------------------------------------------------------------------------
// level-1 histogram: top 16 bits (fine) + top 10 bits (coarse)
__global__ void k_hist1(const float* __restrict__ conf, int n,
                        unsigned* __restrict__ hist, unsigned* __restrict__ coarse) {
    int i = blockIdx.x * blockDim.x + threadIdx.x;
    if (i < n) {
        unsigned u = __float_as_uint(conf[i]);
        atomicAdd(&hist[u >> 16], 1u);
        atomicAdd(&coarse[u >> 22], 1u);
    }
}

// level-2: low 16 bits of elements matching the level-1 prefix
__global__ void k_hist2(const float* __restrict__ conf, int n,
                        const unsigned* __restrict__ ctrl,
                        unsigned* __restrict__ hist, unsigned* __restrict__ coarse) {
    int i = blockIdx.x * blockDim.x + threadIdx.x;
    if (i < n) {
        unsigned u = __float_as_uint(conf[i]);
        if ((u >> 16) == ctrl[3]) {
            atomicAdd(&hist[u & 0xFFFFu], 1u);
            atomicAdd(&coarse[(u & 0xFFFFu) >> 6], 1u);
        }
    }
}

// ---------------------------------------------------------------------------
// coarse suffix-scan (1024 bins) + walk 64 fine bins of the hit chunk.
template <int LEVEL>
__global__ __launch_bounds__(1024) void k_scan(const unsigned* __restrict__ hist,
                                               const unsigned* __restrict__ coarse,
                                               unsigned* __restrict__ ctrl, int ksel) {
    __shared__ unsigned part[1024];
    __shared__ int schunk;
    int t = threadIdx.x;
    unsigned k = (LEVEL == 1) ? (unsigned)ksel : ctrl[4];
    part[t] = coarse[t];
    __syncthreads();
    for (int off = 1; off < 1024; off <<= 1) {
        unsigned v = (t + off < 1024) ? part[t + off] : 0u;
        __syncthreads();
        part[t] += v;
        __syncthreads();
    }
    if (part[t] >= k && (t == 1023 || part[t + 1] < k)) schunk = t;
    __syncthreads();
    if (t == 0) {
        int c = schunk;
        unsigned cum = (c == 1023) ? 0u : part[c + 1];
        int bin = 0; unsigned rem = 1;
        for (int b = 63; b >= 0; b--) {
            unsigned h = hist[c * 64 + b];
            if (cum + h >= k) { bin = c * 64 + b; rem = k - cum; break; }
            cum += h;
        }
        if (LEVEL == 1) { ctrl[3] = (unsigned)bin; ctrl[4] = rem; }
        else {
            ctrl[0] = (ctrl[3] << 16) | (unsigned)bin;
            ctrl[2] = rem;
            ctrl[1] = (unsigned)ksel - rem;
        }
    }
}

// ---------------------------------------------------------------------------
// compact u > T (order within the set irrelevant: loss is set-invariant)
__global__ void k_sel_gt(const float* __restrict__ conf, int n,
                         unsigned* __restrict__ ctrl, int* __restrict__ idx_sel) {
    int i = blockIdx.x * blockDim.x + threadIdx.x;
    if (i < n) {
        if (__float_as_uint(conf[i]) > ctrl[0]) {
            unsigned pos = atomicAdd(&ctrl[5], 1u);
            idx_sel[pos] = i;
        }
    }
}

// compact u == T, lowest indices first (exact jax.lax.top_k tie order)
__global__ __launch_bounds__(1024) void k_sel_eq(const float* __restrict__ conf, int n,
                                                 const unsigned* __restrict__ ctrl,
                                                 int* __restrict__ idx_sel) {
    const int NT = 1024;
    __shared__ unsigned se[NT];
    int t = threadIdx.x;
    unsigned T = ctrl[0], cgt = ctrl[1], neq = ctrl[2];
    int chunk = (n + NT - 1) / NT;
    int lo = t * chunk, hi = min(lo + chunk, n);
    unsigned e = 0;
    for (int i = lo; i < hi; i++)
        if (__float_as_uint(conf[i]) == T) e++;
    se[t] = e;
    __syncthreads();
    for (int off = 1; off < NT; off <<= 1) {
        unsigned v = (t >= off) ? se[t - off] : 0u;
        __syncthreads();
        se[t] += v;
        __syncthreads();
    }
    unsigned ep = se[t] - e;
    for (int i = lo; i < hi; i++)
        if (__float_as_uint(conf[i]) == T) { if (ep < neq) idx_sel[cgt + ep] = i; ep++; }
}

// ---------------------------------------------------------------------------
// gather rows -> bf16, fp32 sq-norms, labels, label histogram; zero-pad
__global__ void k_gather(const float* __restrict__ emb, const int* __restrict__ tags,
                         const int* __restrict__ idx_sel, int ksel, int np,
                         unsigned short* __restrict__ ebf, float* __restrict__ sqn,
                         int* __restrict__ lsel, unsigned* __restrict__ labhist) {
    int j = blockIdx.x;   // < np
    int t = threadIdx.x;  // 64
    if (j < ksel) {
        int src = idx_sel[j];
        float4 v = *(const float4*)&emb[(size_t)src * D + t * 4];
        ushort4 o;
        o.x = f2bf(v.x); o.y = f2bf(v.y); o.z = f2bf(v.z); o.w = f2bf(v.w);
        *(ushort4*)&ebf[(size_t)j * D + t * 4] = o;
        float s = v.x * v.x + v.y * v.y + v.z * v.z + v.w * v.w;
        for (int off = 32; off > 0; off >>= 1) s += __shfl_down(s, off);
        if (t == 0) {
            int lab = tags[src];
            sqn[j] = s; lsel[j] = lab;
            atomicAdd(&labhist[lab], 1u);
        }
    } else {
        ushort4 z = {0, 0, 0, 0};
        *(ushort4*)&ebf[(size_t)j * D + t * 4] = z;
        if (t == 0) { sqn[j] = 0.f; lsel[j] = -1; }
    }
}

// ---------------------------------------------------------------------------
// Fused MFMA GEMM + mining on SQUARED distances. 128x128 triangular blocks,
// 4 waves each 64x64 (4x4 of 16x16x32 frags), BK=64. PASS1: hp2/nm2.
// PASS2: semi-hard min (squared). Distances recomputed bit-identically.
#define LDA 72
template <int PASS>
__global__ __launch_bounds__(256, 2) void k_fused(const unsigned short* __restrict__ Ebf,
                                                  const float* __restrict__ sqn,
                                                  const int* __restrict__ lsel,
                                                  unsigned* __restrict__ hp_g,
                                                  unsigned* __restrict__ nm_g,
                                                  unsigned* __restrict__ shn_g,
                                                  int np, int nb, int ksel) {
    int rem = blockIdx.x, bi = 0;
    while (rem >= nb - bi) { rem -= nb - bi; bi++; }
    int bj = bi + rem;
    int i0 = bi * 128, j0 = bj * 128;
    bool diag = (bi == bj);

    __shared__ __align__(16) char smem[2 * 128 * LDA * 2];  // 36864 B
    unsigned short* As = (unsigned short*)smem;
    unsigned short* Bs = As + 128 * LDA;

    int t = threadIdx.x;
    int w = t >> 6, l = t & 63;
    int wm = w & 1, wn = w >> 1;
    int lr = l & 15, lq = l >> 4;

    f4_t zero = {0.f, 0.f, 0.f, 0.f};
    f4_t acc[4][4];
    #pragma unroll
    for (int p = 0; p < 4; p++)
        #pragma unroll
        for (int q = 0; q < 4; q++) acc[p][q] = zero;

    for (int k0 = 0; k0 < D; k0 += 64) {
        #pragma unroll
        for (int i = 0; i < 4; i++) {
            int idx = t + i * 256;           // 0..1023
            int r = idx >> 3;                // 0..127
            int c = (idx & 7) * 8;           // 0..56
            *(uint4*)&As[r * LDA + c] = *(const uint4*)&Ebf[(size_t)(i0 + r) * D + k0 + c];
            *(uint4*)&Bs[r * LDA + c] = *(const uint4*)&Ebf[(size_t)(j0 + r) * D + k0 + c];
        }
        __syncthreads();
        #pragma unroll
        for (int ks = 0; ks < 64; ks += 32) {
            bf8_t a[4], b[4];
            #pragma unroll
            for (int p = 0; p < 4; p++)
                a[p] = *(bf8_t*)&As[(wm * 64 + p * 16 + lr) * LDA + ks + lq * 8];
            #pragma unroll
            for (int q = 0; q < 4; q++)
                b[q] = *(bf8_t*)&Bs[(wn * 64 + q * 16 + lr) * LDA + ks + lq * 8];
            #pragma unroll
            for (int p = 0; p < 4; p++)
                #pragma unroll
                for (int q = 0; q < 4; q++)
                    acc[p][q] = __builtin_amdgcn_mfma_f32_16x16x32_bf16(a[p], b[q], acc[p][q], 0, 0, 0);
        }
        __syncthreads();
    }

    // stage sqn / labels / (pass2) hp2 into LDS (smem reuse after K-loop)
    float* sqnA = (float*)smem;          // 128
    float* sqnB = sqnA + 128;            // 128
    int* labA = (int*)(sqnB + 128);      // 128
    int* labB = labA + 128;              // 128
    float* hpA2 = (float*)(labB + 128);  // 128
    float* hpB2 = hpA2 + 128;            // 128
    if (t < 128) {
        sqnA[t] = sqn[i0 + t];
        labA[t] = lsel[i0 + t];
        if (PASS == 2) hpA2[t] = __uint_as_float(hp_g[i0 + t]);
    } else {
        int u = t - 128;
        sqnB[u] = sqn[j0 + u];
        labB[u] = lsel[j0 + u];
        if (PASS == 2) hpB2[u] = __uint_as_float(hp_g[j0 + u]);
    }
    __syncthreads();

    // squared distances; C/D map: col = lane&15, row = (lane>>4)*4+reg
    const float INF = __builtin_inff();
    float dsq[4][4][4];
    int colL[4], ljv[4];
    #pragma unroll
    for (int q = 0; q < 4; q++) { colL[q] = wn * 64 + q * 16 + lr; ljv[q] = labB[colL[q]]; }
    #pragma unroll
    for (int p = 0; p < 4; p++) {
        #pragma unroll
        for (int r = 0; r < 4; r++) {
            int rowL = wm * 64 + p * 16 + lq * 4 + r;
            int gm = i0 + rowL;
            float smi = sqnA[rowL];
            #pragma unroll
            for (int q = 0; q < 4; q++) {
                int gn = j0 + colL[q];
                float s = fmaxf(smi + sqnB[colL[q]] - 2.f * acc[p][q][r], 0.f);
                dsq[p][q][r] = (gm < ksel && gn < ksel) ? s : INF;
            }
        }
    }

    // row-direction reduction (all blocks)
    #pragma unroll
    for (int p = 0; p < 4; p++) {
        #pragma unroll
        for (int r = 0; r < 4; r++) {
            int rowL = wm * 64 + p * 16 + lq * 4 + r;
            int li = labA[rowL];
            if (PASS == 1) {
                float hpv = -INF, nmv = INF;
                #pragma unroll
                for (int q = 0; q < 4; q++) {
                    float d = dsq[p][q][r];
                    bool self = diag && (rowL == colL[q]);
                    if (ljv[q] == li) { if (!self) hpv = fmaxf(hpv, d); }
                    else nmv = fminf(nmv, d);
                }
                #pragma unroll
                for (int m = 1; m < 16; m <<= 1) {
                    hpv = fmaxf(hpv, __shfl_xor(hpv, m));
                    nmv = fminf(nmv, __shfl_xor(nmv, m));
                }
                if (lr == 0) {
                    if (hpv >= 0.f) atomicMax(&hp_g[i0 + rowL], __float_as_uint(hpv));
                    if (nmv < INF) atomicMin(&nm_g[i0 + rowL], __float_as_uint(nmv));
                }
            } else {
                float hpr = hpA2[rowL];
                float smv = INF;
                #pragma unroll
                for (int q = 0; q < 4; q++) {
                    float d = dsq[p][q][r];
                    if (ljv[q] != li && d > hpr) smv = fminf(smv, d);
                }
                #pragma unroll
                for (int m = 1; m < 16; m <<= 1) smv = fminf(smv, __shfl_xor(smv, m));
                if (lr == 0 && smv < INF) atomicMin(&shn_g[i0 + rowL], __float_as_uint(smv));
            }
        }
    }

    // column-direction (mirror; off-diagonal blocks only)
    if (!diag) {
        #pragma unroll
        for (int q = 0; q < 4; q++) {
            int lj = ljv[q];
            if (PASS == 1) {
                float hpv = -INF, nmv = INF;
                #pragma unroll
                for (int p = 0; p < 4; p++)
                    #pragma unroll
                    for (int r = 0; r < 4; r++) {
                        int rowL = wm * 64 + p * 16 + lq * 4 + r;
                        float d = dsq[p][q][r];
                        if (labA[rowL] == lj) hpv = fmaxf(hpv, d);
                        else nmv = fminf(nmv, d);
                    }
                hpv = fmaxf(hpv, __shfl_xor(hpv, 16));
                hpv = fmaxf(hpv, __shfl_xor(hpv, 32));
                nmv = fminf(nmv, __shfl_xor(nmv, 16));
                nmv = fminf(nmv, __shfl_xor(nmv, 32));
                if (lq == 0) {
                    if (hpv >= 0.f) atomicMax(&hp_g[j0 + colL[q]], __float_as_uint(hpv));
                    if (nmv < INF) atomicMin(&nm_g[j0 + colL[q]], __float_as_uint(nmv));
                }
            } else {
                float hpc = hpB2[colL[q]];
                float smv = INF;
                #pragma unroll
                for (int p = 0; p < 4; p++)
                    #pragma unroll
                    for (int r = 0; r < 4; r++) {
                        int rowL = wm * 64 + p * 16 + lq * 4 + r;
                        float d = dsq[p][q][r];
                        if (labA[rowL] != lj && d > hpc) smv = fminf(smv, d);
                    }
                smv = fminf(smv, __shfl_xor(smv, 16));
                smv = fminf(smv, __shfl_xor(smv, 32));
                if (lq == 0 && smv < INF) atomicMin(&shn_g[j0 + colL[q]], __float_as_uint(smv));
            }
        }
    }
}

// ---------------------------------------------------------------------------
// parallel loss reduction (sqrt applied here, once per anchor)
__global__ __launch_bounds__(256) void k_loss(const unsigned* __restrict__ hp,
                                              const unsigned* __restrict__ nm,
                                              const unsigned* __restrict__ shn,
                                              const int* __restrict__ lsel,
                                              const unsigned* __restrict__ labhist,
                                              int ksel, float* __restrict__ fsums) {
    __shared__ float ssum[256], scnt[256];
    int t = threadIdx.x;
    int i = blockIdx.x * 256 + t;
    float sum = 0.f, cnt = 0.f;
    if (i < ksel) {
        int li = lsel[i];
        unsigned h = labhist[li];
        bool valid = (h >= 2u) && ((unsigned)ksel > h);
        float hp2 = __uint_as_float(hp[i]);
        float nm2 = __uint_as_float(nm[i]);
        float sh2 = __uint_as_float(shn[i]);
        float hn2 = isinf(sh2) ? nm2 : sh2;
        float lv = valid ? fmaxf(sqrtf(hp2) - sqrtf(hn2) + MARGIN, 0.f) : 0.f;
        sum = lv;
        cnt = valid ? 1.f : 0.f;
    }
    ssum[t] = sum; scnt[t] = cnt;
    __syncthreads();
    for (int off = 128; off > 0; off >>= 1) {
        if (t < off) { ssum[t] += ssum[t + off]; scnt[t] += scnt[t + off]; }
        __syncthreads();
    }
    if (t == 0) { atomicAdd(&fsums[0], ssum[0]); atomicAdd(&fsums[1], scnt[0]); }
}

__global__ void k_out(const float* __restrict__ fsums, float* __restrict__ out) {
    float c = fsums[1];
    out[0] = (c > 0.f) ? (fsums[0] / fmaxf(c, 1.f)) : 0.f;
}

__global__ void k_wsfail(float* out, float code) { out[0] = code; }

// ---------------------------------------------------------------------------
static inline size_t align_up(size_t x, size_t a) { return (x + a - 1) & ~(a - 1); }

extern "C" void kernel_launch(void* const* d_in, const int* in_sizes, int n_in,
                              void* d_out, int out_size, void* d_ws, size_t ws_size,
                              hipStream_t stream) {
    const float* emb  = (const float*)d_in[0];
    const int*   tags = (const int*)d_in[1];
    const float* conf = (const float*)d_in[2];
    float* out = (float*)d_out;

    int n = in_sizes[2];                        // 32768
    int ksel = (int)(0.2 * (double)n);          // 6553
    int np = ((ksel + 127) / 128) * 128;        // 6656
    int nb = np / 128;                          // 52

    size_t off = 0;
    size_t o_ctrl = off; off = align_up(off + 8 * sizeof(unsigned), 256);
    size_t o_fs   = off; off = align_up(off + 8 * sizeof(float), 256);
    size_t o_lh   = off; off = align_up(off + 512 * 4, 256);
    size_t o_idx  = off; off = align_up(off + (size_t)ksel * 4, 256);
    size_t o_lab  = off; off = align_up(off + (size_t)np * 4, 256);
    size_t o_sqn  = off; off = align_up(off + (size_t)np * 4, 256);
    size_t o_hp   = off; off = align_up(off + (size_t)np * 4, 256);
    size_t o_nm   = off; off = align_up(off + (size_t)np * 4, 256);
    size_t o_shn  = off; off = align_up(off + (size_t)np * 4, 256);
    size_t o_h1   = off; off = align_up(off + 65536 * 4, 256);
    size_t o_h2   = off; off = align_up(off + 65536 * 4, 256);
    size_t o_h1c  = off; off = align_up(off + 1024 * 4, 256);
    size_t o_h2c  = off; off = align_up(off + 1024 * 4, 256);
    size_t o_ebf  = off; off = align_up(off + (size_t)np * D * 2, 256);

    if (ws_size < off) {
        k_wsfail<<<1, 1, 0, stream>>>(out, -(float)(ws_size >> 20));
        return;
    }

    char* ws = (char*)d_ws;
    unsigned*       ctrl    = (unsigned*)(ws + o_ctrl);
    float*          fsums   = (float*)(ws + o_fs);
    unsigned*       labhist = (unsigned*)(ws + o_lh);
    int*            idx_sel = (int*)(ws + o_idx);
    int*            lsel    = (int*)(ws + o_lab);
    float*          sqn     = (float*)(ws + o_sqn);
    unsigned*       hp_g    = (unsigned*)(ws + o_hp);
    unsigned*       nm_g    = (unsigned*)(ws + o_nm);
    unsigned*       shn_g   = (unsigned*)(ws + o_shn);
    unsigned*       h1      = (unsigned*)(ws + o_h1);
    unsigned*       h2      = (unsigned*)(ws + o_h2);
    unsigned*       h1c     = (unsigned*)(ws + o_h1c);
    unsigned*       h2c     = (unsigned*)(ws + o_h2c);
    unsigned short* ebf     = (unsigned short*)(ws + o_ebf);

    k_init<<<256, 256, 0, stream>>>(hp_g, nm_g, shn_g, np, h1, h2, h1c, h2c,
                                    labhist, fsums, ctrl);
    k_hist1<<<(n + 255) / 256, 256, 0, stream>>>(conf, n, h1, h1c);
    k_scan<1><<<1, 1024, 0, stream>>>(h1, h1c, ctrl, ksel);
    k_hist2<<<(n + 255) / 256, 256, 0, stream>>>(conf, n, ctrl, h2, h2c);
    k_scan<2><<<1, 1024, 0, stream>>>(h2, h2c, ctrl, ksel);
    k_sel_gt<<<(n + 255) / 256, 256, 0, stream>>>(conf, n, ctrl, idx_sel);
    k_sel_eq<<<1, 1024, 0, stream>>>(conf, n, ctrl, idx_sel);
    k_gather<<<np, 64, 0, stream>>>(emb, tags, idx_sel, ksel, np, ebf, sqn, lsel, labhist);
    int ntri = nb * (nb + 1) / 2;
    k_fused<1><<<ntri, 256, 0, stream>>>(ebf, sqn, lsel, hp_g, nm_g, shn_g, np, nb, ksel);
    k_fused<2><<<ntri, 256, 0, stream>>>(ebf, sqn, lsel, hp_g, nm_g, shn_g, np, nb, ksel);
    k_loss<<<(ksel + 255) / 256, 256, 0, stream>>>(hp_g, nm_g, shn_g, lsel, labhist, ksel, fsums);
    k_out<<<1, 1, 0, stream>>>(fsums, out);
}

// Round 6
// 229.041 us; speedup vs baseline: 1.5376x; 1.5376x over previous
//
#include <hip/hip_runtime.h>
#include <math.h>

#define D 256
#define MARGIN 0.075f

typedef __bf16 bf8_t __attribute__((ext_vector_type(8)));
typedef float f4_t __attribute__((ext_vector_type(4)));

static __device__ __forceinline__ unsigned short f2bf(float x) {
    unsigned u = __float_as_uint(x);
    unsigned r = (u + 0x7fffu + ((u >> 16) & 1u)) >> 16;  // RNE
    return (unsigned short)r;
}

// min-reduction encoding: store cm = max(~bits(x)); init 0 = empty; decode
// 0 -> +inf, else x = ~cm. Valid for x >= 0 (bits < 0x80000000).
static __device__ __forceinline__ float dec_min(unsigned cm) {
    return (cm == 0u) ? __builtin_inff() : __uint_as_float(~cm);
}

// ---------------------------------------------------------------------------
// level-1 histogram: top 16 bits of the float key (conf >= 0 -> bit order)
__global__ void k_hist1(const float* __restrict__ conf, int n,
                        unsigned* __restrict__ hist) {
    int i = blockIdx.x * blockDim.x + threadIdx.x;
    if (i < n) atomicAdd(&hist[__float_as_uint(conf[i]) >> 16], 1u);
}

// level-2: low 16 bits of elements matching the level-1 prefix
__global__ void k_hist2(const float* __restrict__ conf, int n,
                        const unsigned* __restrict__ ctrl,
                        unsigned* __restrict__ hist) {
    int i = blockIdx.x * blockDim.x + threadIdx.x;
    if (i < n) {
        unsigned u = __float_as_uint(conf[i]);
        if ((u >> 16) == ctrl[3]) atomicAdd(&hist[u & 0xFFFFu], 1u);
    }
}

// ---------------------------------------------------------------------------
// suffix-scan a 65536-bin histogram, locate the k-th largest bin.
// LEVEL 1: k=ksel -> ctrl[3]=prefix, ctrl[4]=rem.
// LEVEL 2: k=ctrl[4] -> ctrl[0]=T, ctrl[1]=count_gt, ctrl[2]=need_eq.
template <int LEVEL>
__global__ __launch_bounds__(1024) void k_scan(const unsigned* __restrict__ hist,
                                               unsigned* __restrict__ ctrl, int ksel) {
    __shared__ unsigned part[1024];
    __shared__ int schunk;
    int t = threadIdx.x;
    unsigned k = (LEVEL == 1) ? (unsigned)ksel : ctrl[4];
    unsigned s = 0;
    const uint4* h4 = (const uint4*)(hist + t * 64);
    #pragma unroll
    for (int b = 0; b < 16; b++) {
        uint4 v = h4[b];
        s += v.x + v.y + v.z + v.w;
    }
    part[t] = s;
    __syncthreads();
    for (int off = 1; off < 1024; off <<= 1) {
        unsigned v = (t + off < 1024) ? part[t + off] : 0u;
        __syncthreads();
        part[t] += v;
        __syncthreads();
    }
    if (part[t] >= k && (t == 1023 || part[t + 1] < k)) schunk = t;
    __syncthreads();
    if (t == 0) {
        int c = schunk;
        unsigned cum = (c == 1023) ? 0u : part[c + 1];
        int bin = 0; unsigned rem = 1;
        for (int b = 63; b >= 0; b--) {
            unsigned h = hist[c * 64 + b];
            if (cum + h >= k) { bin = c * 64 + b; rem = k - cum; break; }
            cum += h;
        }
        if (LEVEL == 1) { ctrl[3] = (unsigned)bin; ctrl[4] = rem; }
        else {
            ctrl[0] = (ctrl[3] << 16) | (unsigned)bin;
            ctrl[2] = rem;
            ctrl[1] = (unsigned)ksel - rem;
        }
    }
}

// ---------------------------------------------------------------------------
// merged selection: blocks [0, G-1) compact u > T via atomic slot (order in
// the selected set is irrelevant to the loss); last block does the ordered
// u == T compaction, lowest indices first (exact jax.lax.top_k tie order).
__global__ __launch_bounds__(256) void k_sel(const float* __restrict__ conf, int n,
                                             unsigned* __restrict__ ctrl,
                                             int* __restrict__ idx_sel) {
    int t = threadIdx.x;
    if (blockIdx.x + 1 < gridDim.x) {
        int i = blockIdx.x * 256 + t;
        if (i < n && __float_as_uint(conf[i]) > ctrl[0]) {
            unsigned pos = atomicAdd(&ctrl[5], 1u);
            idx_sel[pos] = i;
        }
    } else {
        __shared__ unsigned se[256];
        unsigned T = ctrl[0], cgt = ctrl[1], neq = ctrl[2];
        int chunk = (n + 255) / 256;
        int lo = t * chunk, hi = min(lo + chunk, n);
        unsigned e = 0;
        for (int i = lo; i < hi; i++)
            if (__float_as_uint(conf[i]) == T) e++;
        se[t] = e;
        __syncthreads();
        for (int off = 1; off < 256; off <<= 1) {
            unsigned v = (t >= off) ? se[t - off] : 0u;
            __syncthreads();
            se[t] += v;
            __syncthreads();
        }
        unsigned ep = se[t] - e;
        for (int i = lo; i < hi && ep < neq; i++)
            if (__float_as_uint(conf[i]) == T) { idx_sel[cgt + ep] = i; ep++; }
    }
}

// ---------------------------------------------------------------------------
// gather rows -> bf16, fp32 sq-norms, labels, label histogram; zero-pad
__global__ void k_gather(const float* __restrict__ emb, const int* __restrict__ tags,
                         const int* __restrict__ idx_sel, int ksel, int np,
                         unsigned short* __restrict__ ebf, float* __restrict__ sqn,
                         int* __restrict__ lsel, unsigned* __restrict__ labhist) {
    int j = blockIdx.x;   // < np
    int t = threadIdx.x;  // 64
    if (j < ksel) {
        int src = idx_sel[j];
        float4 v = *(const float4*)&emb[(size_t)src * D + t * 4];
        ushort4 o;
        o.x = f2bf(v.x); o.y = f2bf(v.y); o.z = f2bf(v.z); o.w = f2bf(v.w);
        *(ushort4*)&ebf[(size_t)j * D + t * 4] = o;
        float s = v.x * v.x + v.y * v.y + v.z * v.z + v.w * v.w;
        for (int off = 32; off > 0; off >>= 1) s += __shfl_down(s, off);
        if (t == 0) {
            int lab = tags[src];
            sqn[j] = s; lsel[j] = lab;
            atomicAdd(&labhist[lab], 1u);
        }
    } else {
        ushort4 z = {0, 0, 0, 0};
        *(ushort4*)&ebf[(size_t)j * D + t * 4] = z;
        if (t == 0) { sqn[j] = 0.f; lsel[j] = -1; }
    }
}

// ---------------------------------------------------------------------------
// Fused MFMA GEMM + mining on SQUARED distances. 128x128 triangular blocks,
// 4 waves each 64x64 (4x4 of 16x16x32 frags), BK=64. PASS1: hp(max)/nm(min).
// PASS2: semi-hard min. min-reductions use the complement-max encoding.
#define LDA 72
template <int PASS>
__global__ __launch_bounds__(256, 2) void k_fused(const unsigned short* __restrict__ Ebf,
                                                  const float* __restrict__ sqn,
                                                  const int* __restrict__ lsel,
                                                  unsigned* __restrict__ hp_g,
                                                  unsigned* __restrict__ nm_g,
                                                  unsigned* __restrict__ shn_g,
                                                  int np, int nb, int ksel) {
    int rem = blockIdx.x, bi = 0;
    while (rem >= nb - bi) { rem -= nb - bi; bi++; }
    int bj = bi + rem;
    int i0 = bi * 128, j0 = bj * 128;
    bool diag = (bi == bj);

    __shared__ __align__(16) char smem[2 * 128 * LDA * 2];  // 36864 B
    unsigned short* As = (unsigned short*)smem;
    unsigned short* Bs = As + 128 * LDA;

    int t = threadIdx.x;
    int w = t >> 6, l = t & 63;
    int wm = w & 1, wn = w >> 1;
    int lr = l & 15, lq = l >> 4;

    f4_t zero = {0.f, 0.f, 0.f, 0.f};
    f4_t acc[4][4];
    #pragma unroll
    for (int p = 0; p < 4; p++)
        #pragma unroll
        for (int q = 0; q < 4; q++) acc[p][q] = zero;

    for (int k0 = 0; k0 < D; k0 += 64) {
        #pragma unroll
        for (int i = 0; i < 4; i++) {
            int idx = t + i * 256;           // 0..1023
            int r = idx >> 3;                // 0..127
            int c = (idx & 7) * 8;           // 0..56
            *(uint4*)&As[r * LDA + c] = *(const uint4*)&Ebf[(size_t)(i0 + r) * D + k0 + c];
            *(uint4*)&Bs[r * LDA + c] = *(const uint4*)&Ebf[(size_t)(j0 + r) * D + k0 + c];
        }
        __syncthreads();
        #pragma unroll
        for (int ks = 0; ks < 64; ks += 32) {
            bf8_t a[4], b[4];
            #pragma unroll
            for (int p = 0; p < 4; p++)
                a[p] = *(bf8_t*)&As[(wm * 64 + p * 16 + lr) * LDA + ks + lq * 8];
            #pragma unroll
            for (int q = 0; q < 4; q++)
                b[q] = *(bf8_t*)&Bs[(wn * 64 + q * 16 + lr) * LDA + ks + lq * 8];
            #pragma unroll
            for (int p = 0; p < 4; p++)
                #pragma unroll
                for (int q = 0; q < 4; q++)
                    acc[p][q] = __builtin_amdgcn_mfma_f32_16x16x32_bf16(a[p], b[q], acc[p][q], 0, 0, 0);
        }
        __syncthreads();
    }

    // stage sqn / labels / (pass2) hp into LDS (smem reuse after K-loop)
    float* sqnA = (float*)smem;          // 128
    float* sqnB = sqnA + 128;            // 128
    int* labA = (int*)(sqnB + 128);      // 128
    int* labB = labA + 128;              // 128
    float* hpA2 = (float*)(labB + 128);  // 128
    float* hpB2 = hpA2 + 128;            // 128
    if (t < 128) {
        sqnA[t] = sqn[i0 + t];
        labA[t] = lsel[i0 + t];
        if (PASS == 2) hpA2[t] = __uint_as_float(hp_g[i0 + t]);
    } else {
        int u = t - 128;
        sqnB[u] = sqn[j0 + u];
        labB[u] = lsel[j0 + u];
        if (PASS == 2) hpB2[u] = __uint_as_float(hp_g[j0 + u]);
    }
    __syncthreads();

    // squared distances; C/D map: col = lane&15, row = (lane>>4)*4+reg
    const float INF = __builtin_inff();
    float dsq[4][4][4];
    int colL[4], ljv[4];
    #pragma unroll
    for (int q = 0; q < 4; q++) { colL[q] = wn * 64 + q * 16 + lr; ljv[q] = labB[colL[q]]; }
    #pragma unroll
    for (int p = 0; p < 4; p++) {
        #pragma unroll
        for (int r = 0; r < 4; r++) {
            int rowL = wm * 64 + p * 16 + lq * 4 + r;
            int gm = i0 + rowL;
            float smi = sqnA[rowL];
            #pragma unroll
            for (int q = 0; q < 4; q++) {
                int gn = j0 + colL[q];
                float s = fmaxf(smi + sqnB[colL[q]] - 2.f * acc[p][q][r], 0.f);
                dsq[p][q][r] = (gm < ksel && gn < ksel) ? s : INF;
            }
        }
    }

    // row-direction reduction (all blocks)
    #pragma unroll
    for (int p = 0; p < 4; p++) {
        #pragma unroll
        for (int r = 0; r < 4; r++) {
            int rowL = wm * 64 + p * 16 + lq * 4 + r;
            int li = labA[rowL];
            if (PASS == 1) {
                float hpv = -INF, nmv = INF;
                #pragma unroll
                for (int q = 0; q < 4; q++) {
                    float d = dsq[p][q][r];
                    bool self = diag && (rowL == colL[q]);
                    if (ljv[q] == li) { if (!self) hpv = fmaxf(hpv, d); }
                    else nmv = fminf(nmv, d);
                }
                #pragma unroll
                for (int m = 1; m < 16; m <<= 1) {
                    hpv = fmaxf(hpv, __shfl_xor(hpv, m));
                    nmv = fminf(nmv, __shfl_xor(nmv, m));
                }
                if (lr == 0) {
                    if (hpv >= 0.f) atomicMax(&hp_g[i0 + rowL], __float_as_uint(hpv));
                    if (nmv < INF) atomicMax(&nm_g[i0 + rowL], ~__float_as_uint(nmv));
                }
            } else {
                float hpr = hpA2[rowL];
                float smv = INF;
                #pragma unroll
                for (int q = 0; q < 4; q++) {
                    float d = dsq[p][q][r];
                    if (ljv[q] != li && d > hpr) smv = fminf(smv, d);
                }
                #pragma unroll
                for (int m = 1; m < 16; m <<= 1) smv = fminf(smv, __shfl_xor(smv, m));
                if (lr == 0 && smv < INF) atomicMax(&shn_g[i0 + rowL], ~__float_as_uint(smv));
            }
        }
    }

    // column-direction (mirror; off-diagonal blocks only)
    if (!diag) {
        #pragma unroll
        for (int q = 0; q < 4; q++) {
            int lj = ljv[q];
            if (PASS == 1) {
                float hpv = -INF, nmv = INF;
                #pragma unroll
                for (int p = 0; p < 4; p++)
                    #pragma unroll
                    for (int r = 0; r < 4; r++) {
                        int rowL = wm * 64 + p * 16 + lq * 4 + r;
                        float d = dsq[p][q][r];
                        if (labA[rowL] == lj) hpv = fmaxf(hpv, d);
                        else nmv = fminf(nmv, d);
                    }
                hpv = fmaxf(hpv, __shfl_xor(hpv, 16));
                hpv = fmaxf(hpv, __shfl_xor(hpv, 32));
                nmv = fminf(nmv, __shfl_xor(nmv, 16));
                nmv = fminf(nmv, __shfl_xor(nmv, 32));
                if (lq == 0) {
                    if (hpv >= 0.f) atomicMax(&hp_g[j0 + colL[q]], __float_as_uint(hpv));
                    if (nmv < INF) atomicMax(&nm_g[j0 + colL[q]], ~__float_as_uint(nmv));
                }
            } else {
                float hpc = hpB2[colL[q]];
                float smv = INF;
                #pragma unroll
                for (int p = 0; p < 4; p++)
                    #pragma unroll
                    for (int r = 0; r < 4; r++) {
                        int rowL = wm * 64 + p * 16 + lq * 4 + r;
                        float d = dsq[p][q][r];
                        if (labA[rowL] != lj && d > hpc) smv = fminf(smv, d);
                    }
                smv = fminf(smv, __shfl_xor(smv, 16));
                smv = fminf(smv, __shfl_xor(smv, 32));
                if (lq == 0 && smv < INF) atomicMax(&shn_g[j0 + colL[q]], ~__float_as_uint(smv));
            }
        }
    }
}

// ---------------------------------------------------------------------------
// parallel loss reduction (sqrt applied here, once per anchor)
__global__ __launch_bounds__(256) void k_loss(const unsigned* __restrict__ hp,
                                              const unsigned* __restrict__ nm,
                                              const unsigned* __restrict__ shn,
                                              const int* __restrict__ lsel,
                                              const unsigned* __restrict__ labhist,
                                              int ksel, float* __restrict__ fsums) {
    __shared__ float ssum[256], scnt[256];
    int t = threadIdx.x;
    int i = blockIdx.x * 256 + t;
    float sum = 0.f, cnt = 0.f;
    if (i < ksel) {
        int li = lsel[i];
        unsigned h = labhist[li];
        bool valid = (h >= 2u) && ((unsigned)ksel > h);
        float hp2 = __uint_as_float(hp[i]);
        float nm2 = dec_min(nm[i]);
        float sh2 = dec_min(shn[i]);
        float hn2 = isinf(sh2) ? nm2 : sh2;
        float lv = valid ? fmaxf(sqrtf(hp2) - sqrtf(hn2) + MARGIN, 0.f) : 0.f;
        sum = lv;
        cnt = valid ? 1.f : 0.f;
    }
    ssum[t] = sum; scnt[t] = cnt;
    __syncthreads();
    for (int off = 128; off > 0; off >>= 1) {
        if (t < off) { ssum[t] += ssum[t + off]; scnt[t] += scnt[t + off]; }
        __syncthreads();
    }
    if (t == 0) { atomicAdd(&fsums[0], ssum[0]); atomicAdd(&fsums[1], scnt[0]); }
}

__global__ void k_out(const float* __restrict__ fsums, float* __restrict__ out) {
    float c = fsums[1];
    out[0] = (c > 0.f) ? (fsums[0] / fmaxf(c, 1.f)) : 0.f;
}

__global__ void k_wsfail(float* out, float code) { out[0] = code; }

// ---------------------------------------------------------------------------
static inline size_t align_up(size_t x, size_t a) { return (x + a - 1) & ~(a - 1); }

extern "C" void kernel_launch(void* const* d_in, const int* in_sizes, int n_in,
                              void* d_out, int out_size, void* d_ws, size_t ws_size,
                              hipStream_t stream) {
    const float* emb  = (const float*)d_in[0];
    const int*   tags = (const int*)d_in[1];
    const float* conf = (const float*)d_in[2];
    float* out = (float*)d_out;

    int n = in_sizes[2];                        // 32768
    int ksel = (int)(0.2 * (double)n);          // 6553
    int np = ((ksel + 127) / 128) * 128;        // 6656
    int nb = np / 128;                          // 52

    // ---- zero-init region (single hipMemsetAsync covers all of it) ----
    size_t off = 0;
    size_t o_ctrl = off; off = align_up(off + 8 * sizeof(unsigned), 256);
    size_t o_fs   = off; off = align_up(off + 8 * sizeof(float), 256);
    size_t o_lh   = off; off = align_up(off + 512 * 4, 256);
    size_t o_hp   = off; off = align_up(off + (size_t)np * 4, 256);
    size_t o_nm   = off; off = align_up(off + (size_t)np * 4, 256);
    size_t o_shn  = off; off = align_up(off + (size_t)np * 4, 256);
    size_t o_h1   = off; off = align_up(off + 65536 * 4, 256);
    size_t o_h2   = off; off = align_up(off + 65536 * 4, 256);
    size_t zero_bytes = off;
    // ---- non-zeroed ----
    size_t o_idx  = off; off = align_up(off + (size_t)ksel * 4, 256);
    size_t o_lab  = off; off = align_up(off + (size_t)np * 4, 256);
    size_t o_sqn  = off; off = align_up(off + (size_t)np * 4, 256);
    size_t o_ebf  = off; off = align_up(off + (size_t)np * D * 2, 256);

    if (ws_size < off) {
        k_wsfail<<<1, 1, 0, stream>>>(out, -(float)(ws_size >> 20));
        return;
    }

    char* ws = (char*)d_ws;
    unsigned*       ctrl    = (unsigned*)(ws + o_ctrl);
    float*          fsums   = (float*)(ws + o_fs);
    unsigned*       labhist = (unsigned*)(ws + o_lh);
    unsigned*       hp_g    = (unsigned*)(ws + o_hp);
    unsigned*       nm_g    = (unsigned*)(ws + o_nm);
    unsigned*       shn_g   = (unsigned*)(ws + o_shn);
    unsigned*       h1      = (unsigned*)(ws + o_h1);
    unsigned*       h2      = (unsigned*)(ws + o_h2);
    int*            idx_sel = (int*)(ws + o_idx);
    int*            lsel    = (int*)(ws + o_lab);
    float*          sqn     = (float*)(ws + o_sqn);
    unsigned short* ebf     = (unsigned short*)(ws + o_ebf);

    hipMemsetAsync(d_ws, 0, zero_bytes, stream);
    k_hist1<<<(n + 255) / 256, 256, 0, stream>>>(conf, n, h1);
    k_scan<1><<<1, 1024, 0, stream>>>(h1, ctrl, ksel);
    k_hist2<<<(n + 255) / 256, 256, 0, stream>>>(conf, n, ctrl, h2);
    k_scan<2><<<1, 1024, 0, stream>>>(h2, ctrl, ksel);
    k_sel<<<(n + 255) / 256 + 1, 256, 0, stream>>>(conf, n, ctrl, idx_sel);
    k_gather<<<np, 64, 0, stream>>>(emb, tags, idx_sel, ksel, np, ebf, sqn, lsel, labhist);
    int ntri = nb * (nb + 1) / 2;
    k_fused<1><<<ntri, 256, 0, stream>>>(ebf, sqn, lsel, hp_g, nm_g, shn_g, np, nb, ksel);
    k_fused<2><<<ntri, 256, 0, stream>>>(ebf, sqn, lsel, hp_g, nm_g, shn_g, np, nb, ksel);
    k_loss<<<(ksel + 255) / 256, 256, 0, stream>>>(hp_g, nm_g, shn_g, lsel, labhist, ksel, fsums);
    k_out<<<1, 1, 0, stream>>>(fsums, out);
}

// Round 7
// 201.113 us; speedup vs baseline: 1.7511x; 1.1389x over previous
//
#include <hip/hip_runtime.h>
#include <math.h>

#define D 256
#define MARGIN 0.075f

typedef __bf16 bf8_t __attribute__((ext_vector_type(8)));
typedef float f4_t __attribute__((ext_vector_type(4)));
typedef unsigned long long ull;

#define AS1 __attribute__((address_space(1)))
#define AS3 __attribute__((address_space(3)))
static __device__ __forceinline__ void gload_lds16(const void* g, void* s) {
    __builtin_amdgcn_global_load_lds((const AS1 unsigned int*)g, (AS3 unsigned int*)s, 16, 0, 0);
}

static __device__ __forceinline__ unsigned short f2bf(float x) {
    unsigned u = __float_as_uint(x);
    unsigned r = (u + 0x7fffu + ((u >> 16) & 1u)) >> 16;  // RNE
    return (unsigned short)r;
}

// min-reduction encoding: store cm = max(~bits(x)); init 0 = empty; decode
// 0 -> +inf, else x = ~cm. Valid for x >= 0.
static __device__ __forceinline__ float dec_min(unsigned cm) {
    return (cm == 0u) ? __builtin_inff() : __uint_as_float(~cm);
}

// ---------------------------------------------------------------------------
// 16-bit histogram of the float keys (conf >= 0 -> bit order = value order)
__global__ void k_hist1(const float* __restrict__ conf, int n,
                        unsigned* __restrict__ hist) {
    int i = blockIdx.x * blockDim.x + threadIdx.x;
    if (i < n) atomicAdd(&hist[__float_as_uint(conf[i]) >> 16], 1u);
}

// suffix-scan the 65536-bin histogram: find bin b16 such that
// count(t16 > b16) < ksel <= count(t16 >= b16).
// ctrl[3]=b16, ctrl[1]=count_gt16, ctrl[2]=need (from the boundary bin)
__global__ __launch_bounds__(1024) void k_scan(const unsigned* __restrict__ hist,
                                               unsigned* __restrict__ ctrl, int ksel) {
    __shared__ unsigned part[1024];
    __shared__ int schunk;
    int t = threadIdx.x;
    unsigned k = (unsigned)ksel;
    unsigned s = 0;
    const uint4* h4 = (const uint4*)(hist + t * 64);
    #pragma unroll
    for (int b = 0; b < 16; b++) {
        uint4 v = h4[b];
        s += v.x + v.y + v.z + v.w;
    }
    part[t] = s;
    __syncthreads();
    for (int off = 1; off < 1024; off <<= 1) {
        unsigned v = (t + off < 1024) ? part[t + off] : 0u;
        __syncthreads();
        part[t] += v;
        __syncthreads();
    }
    if (part[t] >= k && (t == 1023 || part[t + 1] < k)) schunk = t;
    __syncthreads();
    if (t == 0) {
        int c = schunk;
        unsigned cum = (c == 1023) ? 0u : part[c + 1];
        int bin = 0; unsigned rem = 1;
        for (int b = 63; b >= 0; b--) {
            unsigned h = hist[c * 64 + b];
            if (cum + h >= k) { bin = c * 64 + b; rem = k - cum; break; }
            cum += h;
        }
        ctrl[3] = (unsigned)bin;
        ctrl[1] = k - rem;    // count strictly above the bin
        ctrl[2] = rem;        // how many to take from the bin
    }
}

// selection: t16 > b16 -> slot (set order irrelevant to the loss);
// t16 == b16 -> candidate buffer for exact boundary resolution
__global__ void k_sel(const float* __restrict__ conf, int n,
                      unsigned* __restrict__ ctrl, int* __restrict__ idx_sel,
                      ull* __restrict__ cand) {
    int i = blockIdx.x * blockDim.x + threadIdx.x;
    if (i < n) {
        unsigned u = __float_as_uint(conf[i]);
        unsigned t16 = u >> 16, b16 = ctrl[3];
        if (t16 > b16) {
            unsigned pos = atomicAdd(&ctrl[5], 1u);
            idx_sel[pos] = i;
        } else if (t16 == b16) {
            unsigned pos = atomicAdd(&ctrl[6], 1u);
            cand[pos] = ((ull)u << 32) | (unsigned)i;
        }
    }
}

// boundary bin: rank by (value desc, index asc) — exact jax.lax.top_k order —
// and keep the best `need` candidates.
__global__ __launch_bounds__(256) void k_sel2(const unsigned* __restrict__ ctrl,
                                              const ull* __restrict__ cand,
                                              int* __restrict__ idx_sel) {
    int t = threadIdx.x;
    int M = (int)ctrl[6];
    unsigned need = ctrl[2], cgt = ctrl[1];
    for (int j = t; j < M; j += 256) {
        ull cj = cand[j];
        unsigned rank = 0;
        for (int m = 0; m < M; m++) {
            ull cm = cand[m];
            unsigned um = (unsigned)(cm >> 32), uj = (unsigned)(cj >> 32);
            // better = larger value, or same value with smaller index
            if (um > uj || (um == uj && cm < cj)) rank++;
        }
        if (rank < need) idx_sel[cgt + rank] = (int)(unsigned)(cj & 0xFFFFFFFFu);
    }
}

// ---------------------------------------------------------------------------
// gather rows -> bf16, fp32 sq-norms, labels, label histogram; zero-pad
__global__ void k_gather(const float* __restrict__ emb, const int* __restrict__ tags,
                         const int* __restrict__ idx_sel, int ksel, int np,
                         unsigned short* __restrict__ ebf, float* __restrict__ sqn,
                         int* __restrict__ lsel, unsigned* __restrict__ labhist) {
    int j = blockIdx.x;   // < np
    int t = threadIdx.x;  // 64
    if (j < ksel) {
        int src = idx_sel[j];
        float4 v = *(const float4*)&emb[(size_t)src * D + t * 4];
        ushort4 o;
        o.x = f2bf(v.x); o.y = f2bf(v.y); o.z = f2bf(v.z); o.w = f2bf(v.w);
        *(ushort4*)&ebf[(size_t)j * D + t * 4] = o;
        float s = v.x * v.x + v.y * v.y + v.z * v.z + v.w * v.w;
        for (int off = 32; off > 0; off >>= 1) s += __shfl_down(s, off);
        if (t == 0) {
            int lab = tags[src];
            sqn[j] = s; lsel[j] = lab;
            atomicAdd(&labhist[lab], 1u);
        }
    } else {
        ushort4 z = {0, 0, 0, 0};
        *(ushort4*)&ebf[(size_t)j * D + t * 4] = z;
        if (t == 0) { sqn[j] = 0.f; lsel[j] = -1; }
    }
}

// ---------------------------------------------------------------------------
// Fused MFMA GEMM + mining on SQUARED distances. 128x128 triangular blocks,
// 4 waves each 64x64 (4x4 of 16x16x32 frags), BK=64.
// Staging: global_load_lds width=16 into XOR-swizzled unpadded LDS tiles.
// LDS layout: tile [128 rows][64 cols bf16], row r, 8-col segment s stored at
//   byte offset (r>>3)*1024 + ((r&7)*8 + (s ^ (r&7)))*16
// which is exactly lane-contiguous for the staging calls below.
template <int PASS>
__global__ __launch_bounds__(256, 3) void k_fused(const unsigned short* __restrict__ Ebf,
                                                  const float* __restrict__ sqn,
                                                  const int* __restrict__ lsel,
                                                  unsigned* __restrict__ hp_g,
                                                  unsigned* __restrict__ nm_g,
                                                  unsigned* __restrict__ shn_g,
                                                  int np, int nb, int ksel) {
    int rem = blockIdx.x, bi = 0;
    while (rem >= nb - bi) { rem -= nb - bi; bi++; }
    int bj = bi + rem;
    int i0 = bi * 128, j0 = bj * 128;
    bool diag = (bi == bj);

    __shared__ __align__(16) char smem[32768];
    char* ldsA = smem;
    char* ldsB = smem + 16384;

    int t = threadIdx.x;
    int w = t >> 6, l = t & 63;
    int wm = w & 1, wn = w >> 1;
    int lr = l & 15, lq = l >> 4;
    int r7 = lr & 7, rh = lr >> 3;

    // staging lane constants: lane l covers row (+dr), segment sg (xor-swizzled)
    int dr = l >> 3;
    int sg = (l & 7) ^ dr;
    const unsigned short* gA = Ebf + (size_t)(i0 + dr) * D + sg * 8;
    const unsigned short* gB = Ebf + (size_t)(j0 + dr) * D + sg * 8;

    f4_t zero = {0.f, 0.f, 0.f, 0.f};
    f4_t acc[4][4];
    #pragma unroll
    for (int p = 0; p < 4; p++)
        #pragma unroll
        for (int q = 0; q < 4; q++) acc[p][q] = zero;

    for (int k0 = 0; k0 < D; k0 += 64) {
        #pragma unroll
        for (int c = 0; c < 4; c++) {
            int R0 = w * 32 + c * 8;
            gload_lds16(gA + (size_t)R0 * D + k0, ldsA + R0 * 128);
            gload_lds16(gB + (size_t)R0 * D + k0, ldsB + R0 * 128);
        }
        __syncthreads();
        #pragma unroll
        for (int ks8 = 0; ks8 < 8; ks8 += 4) {   // ks = ks8*8
            bf8_t a[4], b[4];
            #pragma unroll
            for (int p = 0; p < 4; p++) {
                int off = ((wm * 8 + p * 2 + rh) << 10) + ((r7 * 8 + (((ks8 + lq)) ^ r7)) << 4);
                a[p] = *(const bf8_t*)(ldsA + off);
            }
            #pragma unroll
            for (int q = 0; q < 4; q++) {
                int off = ((wn * 8 + q * 2 + rh) << 10) + ((r7 * 8 + (((ks8 + lq)) ^ r7)) << 4);
                b[q] = *(const bf8_t*)(ldsB + off);
            }
            #pragma unroll
            for (int p = 0; p < 4; p++)
                #pragma unroll
                for (int q = 0; q < 4; q++)
                    acc[p][q] = __builtin_amdgcn_mfma_f32_16x16x32_bf16(a[p], b[q], acc[p][q], 0, 0, 0);
        }
        __syncthreads();
    }

    // stage sqn / labels / (pass2) hp into LDS (smem reuse after K-loop)
    float* sqnA = (float*)smem;          // 128
    float* sqnB = sqnA + 128;            // 128
    int* labA = (int*)(sqnB + 128);      // 128
    int* labB = labA + 128;              // 128
    float* hpA2 = (float*)(labB + 128);  // 128
    float* hpB2 = hpA2 + 128;            // 128
    if (t < 128) {
        sqnA[t] = sqn[i0 + t];
        labA[t] = lsel[i0 + t];
        if (PASS == 2) hpA2[t] = __uint_as_float(hp_g[i0 + t]);
    } else {
        int u = t - 128;
        sqnB[u] = sqn[j0 + u];
        labB[u] = lsel[j0 + u];
        if (PASS == 2) hpB2[u] = __uint_as_float(hp_g[j0 + u]);
    }
    __syncthreads();

    // squared distances; C/D map: col = lane&15, row = (lane>>4)*4+reg
    const float INF = __builtin_inff();
    float dsq[4][4][4];
    int colL[4], ljv[4];
    #pragma unroll
    for (int q = 0; q < 4; q++) { colL[q] = wn * 64 + q * 16 + lr; ljv[q] = labB[colL[q]]; }
    #pragma unroll
    for (int p = 0; p < 4; p++) {
        #pragma unroll
        for (int r = 0; r < 4; r++) {
            int rowL = wm * 64 + p * 16 + lq * 4 + r;
            int gm = i0 + rowL;
            float smi = sqnA[rowL];
            #pragma unroll
            for (int q = 0; q < 4; q++) {
                int gn = j0 + colL[q];
                float s = fmaxf(smi + sqnB[colL[q]] - 2.f * acc[p][q][r], 0.f);
                dsq[p][q][r] = (gm < ksel && gn < ksel) ? s : INF;
            }
        }
    }

    // row-direction reduction (all blocks)
    #pragma unroll
    for (int p = 0; p < 4; p++) {
        #pragma unroll
        for (int r = 0; r < 4; r++) {
            int rowL = wm * 64 + p * 16 + lq * 4 + r;
            int li = labA[rowL];
            if (PASS == 1) {
                float hpv = -INF, nmv = INF;
                #pragma unroll
                for (int q = 0; q < 4; q++) {
                    float d = dsq[p][q][r];
                    bool self = diag && (rowL == colL[q]);
                    if (ljv[q] == li) { if (!self) hpv = fmaxf(hpv, d); }
                    else nmv = fminf(nmv, d);
                }
                #pragma unroll
                for (int m = 1; m < 16; m <<= 1) {
                    hpv = fmaxf(hpv, __shfl_xor(hpv, m));
                    nmv = fminf(nmv, __shfl_xor(nmv, m));
                }
                if (lr == 0) {
                    if (hpv >= 0.f) atomicMax(&hp_g[i0 + rowL], __float_as_uint(hpv));
                    if (nmv < INF) atomicMax(&nm_g[i0 + rowL], ~__float_as_uint(nmv));
                }
            } else {
                float hpr = hpA2[rowL];
                float smv = INF;
                #pragma unroll
                for (int q = 0; q < 4; q++) {
                    float d = dsq[p][q][r];
                    if (ljv[q] != li && d > hpr) smv = fminf(smv, d);
                }
                #pragma unroll
                for (int m = 1; m < 16; m <<= 1) smv = fminf(smv, __shfl_xor(smv, m));
                if (lr == 0 && smv < INF) atomicMax(&shn_g[i0 + rowL], ~__float_as_uint(smv));
            }
        }
    }

    // column-direction (mirror; off-diagonal blocks only)
    if (!diag) {
        #pragma unroll
        for (int q = 0; q < 4; q++) {
            int lj = ljv[q];
            if (PASS == 1) {
                float hpv = -INF, nmv = INF;
                #pragma unroll
                for (int p = 0; p < 4; p++)
                    #pragma unroll
                    for (int r = 0; r < 4; r++) {
                        int rowL = wm * 64 + p * 16 + lq * 4 + r;
                        float d = dsq[p][q][r];
                        if (labA[rowL] == lj) hpv = fmaxf(hpv, d);
                        else nmv = fminf(nmv, d);
                    }
                hpv = fmaxf(hpv, __shfl_xor(hpv, 16));
                hpv = fmaxf(hpv, __shfl_xor(hpv, 32));
                nmv = fminf(nmv, __shfl_xor(nmv, 16));
                nmv = fminf(nmv, __shfl_xor(nmv, 32));
                if (lq == 0) {
                    if (hpv >= 0.f) atomicMax(&hp_g[j0 + colL[q]], __float_as_uint(hpv));
                    if (nmv < INF) atomicMax(&nm_g[j0 + colL[q]], ~__float_as_uint(nmv));
                }
            } else {
                float hpc = hpB2[colL[q]];
                float smv = INF;
                #pragma unroll
                for (int p = 0; p < 4; p++)
                    #pragma unroll
                    for (int r = 0; r < 4; r++) {
                        int rowL = wm * 64 + p * 16 + lq * 4 + r;
                        float d = dsq[p][q][r];
                        if (labA[rowL] != lj && d > hpc) smv = fminf(smv, d);
                    }
                smv = fminf(smv, __shfl_xor(smv, 16));
                smv = fminf(smv, __shfl_xor(smv, 32));
                if (lq == 0 && smv < INF) atomicMax(&shn_g[j0 + colL[q]], ~__float_as_uint(smv));
            }
        }
    }
}

// ---------------------------------------------------------------------------
// loss reduction + final output (last finished block writes out)
__global__ __launch_bounds__(256) void k_loss(const unsigned* __restrict__ hp,
                                              const unsigned* __restrict__ nm,
                                              const unsigned* __restrict__ shn,
                                              const int* __restrict__ lsel,
                                              const unsigned* __restrict__ labhist,
                                              int ksel, float* __restrict__ fsums,
                                              unsigned* __restrict__ ctrl,
                                              float* __restrict__ out) {
    __shared__ float ssum[256], scnt[256];
    int t = threadIdx.x;
    int i = blockIdx.x * 256 + t;
    float sum = 0.f, cnt = 0.f;
    if (i < ksel) {
        int li = lsel[i];
        unsigned h = labhist[li];
        bool valid = (h >= 2u) && ((unsigned)ksel > h);
        float hp2 = __uint_as_float(hp[i]);
        float nm2 = dec_min(nm[i]);
        float sh2 = dec_min(shn[i]);
        float hn2 = isinf(sh2) ? nm2 : sh2;
        float lv = valid ? fmaxf(sqrtf(hp2) - sqrtf(hn2) + MARGIN, 0.f) : 0.f;
        sum = lv;
        cnt = valid ? 1.f : 0.f;
    }
    ssum[t] = sum; scnt[t] = cnt;
    __syncthreads();
    for (int off = 128; off > 0; off >>= 1) {
        if (t < off) { ssum[t] += ssum[t + off]; scnt[t] += scnt[t + off]; }
        __syncthreads();
    }
    if (t == 0) {
        atomicAdd(&fsums[0], ssum[0]);
        atomicAdd(&fsums[1], scnt[0]);
        __threadfence();
        unsigned done = atomicAdd(&ctrl[7], 1u);
        if (done == gridDim.x - 1) {
            float s = atomicAdd(&fsums[0], 0.f);
            float c = atomicAdd(&fsums[1], 0.f);
            out[0] = (c > 0.f) ? (s / fmaxf(c, 1.f)) : 0.f;
        }
    }
}

__global__ void k_wsfail(float* out, float code) { out[0] = code; }

// ---------------------------------------------------------------------------
static inline size_t align_up(size_t x, size_t a) { return (x + a - 1) & ~(a - 1); }

extern "C" void kernel_launch(void* const* d_in, const int* in_sizes, int n_in,
                              void* d_out, int out_size, void* d_ws, size_t ws_size,
                              hipStream_t stream) {
    const float* emb  = (const float*)d_in[0];
    const int*   tags = (const int*)d_in[1];
    const float* conf = (const float*)d_in[2];
    float* out = (float*)d_out;

    int n = in_sizes[2];                        // 32768
    int ksel = (int)(0.2 * (double)n);          // 6553
    int np = ((ksel + 127) / 128) * 128;        // 6656
    int nb = np / 128;                          // 52

    // ---- zero-init region (single hipMemsetAsync covers all of it) ----
    size_t off = 0;
    size_t o_ctrl = off; off = align_up(off + 16 * sizeof(unsigned), 256);
    size_t o_fs   = off; off = align_up(off + 8 * sizeof(float), 256);
    size_t o_lh   = off; off = align_up(off + 512 * 4, 256);
    size_t o_hp   = off; off = align_up(off + (size_t)np * 4, 256);
    size_t o_nm   = off; off = align_up(off + (size_t)np * 4, 256);
    size_t o_shn  = off; off = align_up(off + (size_t)np * 4, 256);
    size_t o_h1   = off; off = align_up(off + 65536 * 4, 256);
    size_t zero_bytes = off;
    // ---- non-zeroed ----
    size_t o_idx  = off; off = align_up(off + (size_t)ksel * 4, 256);
    size_t o_cand = off; off = align_up(off + (size_t)32768 * 8, 256);
    size_t o_lab  = off; off = align_up(off + (size_t)np * 4, 256);
    size_t o_sqn  = off; off = align_up(off + (size_t)np * 4, 256);
    size_t o_ebf  = off; off = align_up(off + (size_t)np * D * 2, 256);

    if (ws_size < off) {
        k_wsfail<<<1, 1, 0, stream>>>(out, -(float)(ws_size >> 20));
        return;
    }

    char* ws = (char*)d_ws;
    unsigned*       ctrl    = (unsigned*)(ws + o_ctrl);
    float*          fsums   = (float*)(ws + o_fs);
    unsigned*       labhist = (unsigned*)(ws + o_lh);
    unsigned*       hp_g    = (unsigned*)(ws + o_hp);
    unsigned*       nm_g    = (unsigned*)(ws + o_nm);
    unsigned*       shn_g   = (unsigned*)(ws + o_shn);
    unsigned*       h1      = (unsigned*)(ws + o_h1);
    int*            idx_sel = (int*)(ws + o_idx);
    ull*            cand    = (ull*)(ws + o_cand);
    int*            lsel    = (int*)(ws + o_lab);
    float*          sqn     = (float*)(ws + o_sqn);
    unsigned short* ebf     = (unsigned short*)(ws + o_ebf);

    hipMemsetAsync(d_ws, 0, zero_bytes, stream);
    k_hist1<<<(n + 255) / 256, 256, 0, stream>>>(conf, n, h1);
    k_scan<<<1, 1024, 0, stream>>>(h1, ctrl, ksel);
    k_sel<<<(n + 255) / 256, 256, 0, stream>>>(conf, n, ctrl, idx_sel, cand);
    k_sel2<<<1, 256, 0, stream>>>(ctrl, cand, idx_sel);
    k_gather<<<np, 64, 0, stream>>>(emb, tags, idx_sel, ksel, np, ebf, sqn, lsel, labhist);
    int ntri = nb * (nb + 1) / 2;
    k_fused<1><<<ntri, 256, 0, stream>>>(ebf, sqn, lsel, hp_g, nm_g, shn_g, np, nb, ksel);
    k_fused<2><<<ntri, 256, 0, stream>>>(ebf, sqn, lsel, hp_g, nm_g, shn_g, np, nb, ksel);
    k_loss<<<(ksel + 255) / 256, 256, 0, stream>>>(hp_g, nm_g, shn_g, lsel, labhist,
                                                   ksel, fsums, ctrl, out);
}